// Round 1
// baseline (50.987 us; speedup 1.0000x reference)
//
#include <hip/hip_runtime.h>
#include <hip/hip_bf16.h>

// Problem: B=24, L=512, D=64, H=64
//   h = gelu(x @ W + b)                        [24,512,64]
//   S = einsum('ilh,jmh->ijlm', h, h)          [24,24,512,512]
//   scores = logsumexp(S, axis=(2,3))          [24,24]  (TAU=1)
//
// Strategy: h fits L2 (1.5MB as bf16). scores = log(sum_{l,m} 2^(S*log2e)).
// Pre-scale one operand by log2e so MFMA output feeds v_exp_f32 directly.
// Only 300 unique (i<=j) pairs; mirror at the end. No max-shift needed:
// S <= ~30 -> sum <= 2.6e18 < f32 max; sum > 0 always.

#define LOG2E 1.4426950408889634f

typedef unsigned short u16;
typedef __attribute__((ext_vector_type(8))) short bf16x8;
typedef __attribute__((ext_vector_type(4))) float f32x4;

// ---------------- encoder: h = gelu(x@W+b), write bf16 h and h*log2e ------
__global__ __launch_bounds__(256) void encode_kernel(
    const float* __restrict__ x, const float* __restrict__ W,
    const float* __restrict__ bias, u16* __restrict__ hb,
    u16* __restrict__ hlb) {
  int lane = threadIdx.x & 63;
  int row = blockIdx.x * 4 + (threadIdx.x >> 6);   // 12288 rows total
  float xv = x[row * 64 + lane];
  float acc = bias[lane];
#pragma unroll
  for (int d = 0; d < 64; ++d) {
    float xs = __shfl(xv, d, 64);
    acc = fmaf(xs, W[d * 64 + lane], acc);
  }
  // JAX default gelu (approximate=True, tanh form)
  float z = acc;
  float t = tanhf(0.7978845608028654f * (z + 0.044715f * z * z * z));
  float g = 0.5f * z * (1.0f + t);
  __hip_bfloat16 hg = __float2bfloat16(g);
  __hip_bfloat16 hgl = __float2bfloat16(g * LOG2E);
  hb[row * 64 + lane] = *reinterpret_cast<u16*>(&hg);
  hlb[row * 64 + lane] = *reinterpret_cast<u16*>(&hgl);
}

// ---------------- pair kernel: one (i<=j) pair split into 2 half-tiles ----
// Block = 256 thr (4 waves). Wave owns a 64-row A band (held in registers),
// sweeps all 512 B columns. MFMA 16x16x32 bf16; per output fragment do
// 4x v_exp_f32 (=2^x since B operand pre-scaled by log2e) + accumulate.
__global__ __launch_bounds__(256) void pair_kernel(
    const u16* __restrict__ hb, const u16* __restrict__ hlb,
    float* __restrict__ sums) {
  int p = blockIdx.x >> 1;
  int half = blockIdx.x & 1;
  // decode triangular index p -> (i,j), i<=j
  int i = 0, rem = p;
  while (rem >= 24 - i) { rem -= 24 - i; ++i; }
  int j = i + rem;

  const u16* Ap = hb + (size_t)i * 512 * 64;
  const u16* Bp = hlb + (size_t)j * 512 * 64;

  int wid = threadIdx.x >> 6;
  int lane = threadIdx.x & 63;
  int r = lane & 15;        // row within 16-row fragment
  int kg = lane >> 4;       // k-group (8 contiguous bf16 each)
  int row0 = half * 256 + wid * 64;

  // A fragments for this wave's 64 rows, K=64 (2 k-halves)
  bf16x8 a[4][2];
#pragma unroll
  for (int rm = 0; rm < 4; ++rm)
#pragma unroll
    for (int kf = 0; kf < 2; ++kf)
      a[rm][kf] = *reinterpret_cast<const bf16x8*>(
          Ap + (size_t)(row0 + rm * 16 + r) * 64 + kf * 32 + kg * 8);

  float s0 = 0.f, s1 = 0.f, s2 = 0.f, s3 = 0.f;
  const f32x4 zero = {0.f, 0.f, 0.f, 0.f};

  for (int cn = 0; cn < 32; ++cn) {
    const u16* brow = Bp + (size_t)(cn * 16 + r) * 64 + kg * 8;
    bf16x8 b0 = *reinterpret_cast<const bf16x8*>(brow);
    bf16x8 b1 = *reinterpret_cast<const bf16x8*>(brow + 32);
#pragma unroll
    for (int rm = 0; rm < 4; ++rm) {
      f32x4 acc = __builtin_amdgcn_mfma_f32_16x16x32_bf16(a[rm][0], b0, zero, 0, 0, 0);
      acc = __builtin_amdgcn_mfma_f32_16x16x32_bf16(a[rm][1], b1, acc, 0, 0, 0);
      float e0, e1, e2, e3;
      asm("v_exp_f32 %0, %1" : "=v"(e0) : "v"(acc[0]));
      asm("v_exp_f32 %0, %1" : "=v"(e1) : "v"(acc[1]));
      asm("v_exp_f32 %0, %1" : "=v"(e2) : "v"(acc[2]));
      asm("v_exp_f32 %0, %1" : "=v"(e3) : "v"(acc[3]));
      s0 += e0; s1 += e1; s2 += e2; s3 += e3;
    }
  }
  float sum = (s0 + s1) + (s2 + s3);
#pragma unroll
  for (int off = 32; off >= 1; off >>= 1) sum += __shfl_xor(sum, off, 64);
  if (lane == 0) atomicAdd(&sums[p], sum);
}

// ---------------- finalize: log + mirror to full 24x24 --------------------
__global__ void finish_kernel(const float* __restrict__ sums,
                              float* __restrict__ out) {
  int t = threadIdx.x + blockIdx.x * blockDim.x;
  if (t >= 576) return;
  int i = t / 24, j = t % 24;
  int ii = i < j ? i : j, jj = i < j ? j : i;
  int p = ii * 24 - ii * (ii - 1) / 2 + (jj - ii);
  out[t] = logf(sums[p]);
}

extern "C" void kernel_launch(void* const* d_in, const int* in_sizes, int n_in,
                              void* d_out, int out_size, void* d_ws,
                              size_t ws_size, hipStream_t stream) {
  const float* x = (const float*)d_in[0];
  const float* W = (const float*)d_in[1];
  const float* bias = (const float*)d_in[2];
  float* out = (float*)d_out;

  u16* hb = (u16*)d_ws;                  // 12288*64 bf16 = 1.50 MiB
  u16* hlb = hb + 12288 * 64;            // 1.50 MiB
  float* sums = (float*)(hlb + 12288 * 64);  // 300 floats

  hipMemsetAsync(sums, 0, 300 * sizeof(float), stream);
  encode_kernel<<<3072, 256, 0, stream>>>(x, W, bias, hb, hlb);
  pair_kernel<<<600, 256, 0, stream>>>(hb, hlb, sums);
  finish_kernel<<<9, 64, 0, stream>>>(sums, out);
}